// Round 1
// baseline (1479.321 us; speedup 1.0000x reference)
//
#include <hip/hip_runtime.h>

#define D 64

// One wave (64 lanes) per edge: lane = feature dim. Gather feat[src][lane],
// atomicAdd into acc[dst][lane]; lane 0 bumps the in-degree counter.
__global__ __launch_bounds__(256) void scatter_mean(
    const float* __restrict__ feat,
    const int* __restrict__ src,
    const int* __restrict__ dst,
    float* __restrict__ acc,
    int* __restrict__ cnt,
    int nE)
{
    const int lane = threadIdx.x & 63;
    const int wave = (int)((blockIdx.x * blockDim.x + threadIdx.x) >> 6);
    const int nwave = (int)((gridDim.x * blockDim.x) >> 6);
    for (int e = wave; e < nE; e += nwave) {
        const int s = src[e];
        const int d = dst[e];
        const float v = feat[s * D + lane];
        atomicAdd(&acc[d * D + lane], v);
        if (lane == 0) atomicAdd(&cnt[d], 1);
    }
}

// Per-node finalize: h[n] = mean_A[n] @ WA.T + bA*[cntA>0]  (+ same for B).
// One wave per node; W transposed into LDS so lane-d reads WT[k][d] conflict-free.
template <bool TWO>
__global__ __launch_bounds__(256) void finalize_nodes(
    const float* __restrict__ accA, const int* __restrict__ cntA,
    const float* __restrict__ WA, const float* __restrict__ bA,
    const float* __restrict__ accB, const int* __restrict__ cntB,
    const float* __restrict__ WB, const float* __restrict__ bB,
    float* __restrict__ out, int N)
{
    __shared__ float WTa[64][64];
    __shared__ float WTb[TWO ? 64 : 1][64];
    __shared__ float bsA[64];
    __shared__ float bsB[64];
    for (int i = threadIdx.x; i < 4096; i += 256) {
        const int d = i >> 6, k = i & 63;
        WTa[k][d] = WA[i];
        if (TWO) WTb[k][d] = WB[i];
    }
    if (threadIdx.x < 64) {
        bsA[threadIdx.x] = bA[threadIdx.x];
        bsB[threadIdx.x] = TWO ? bB[threadIdx.x] : 0.0f;
    }
    __syncthreads();

    const int lane = threadIdx.x & 63;
    const int w = threadIdx.x >> 6;  // 4 waves per block, 1 node per wave
    for (int n = blockIdx.x * 4 + w; n < N; n += gridDim.x * 4) {
        const int ca = cntA[n];
        const float inva = ca > 0 ? 1.0f / (float)ca : 0.0f;
        float xa = accA[n * 64 + lane] * inva;
        float s = ca > 0 ? bsA[lane] : 0.0f;
        float xb = 0.0f;
        if (TWO) {
            const int cb = cntB[n];
            const float invb = cb > 0 ? 1.0f / (float)cb : 0.0f;
            xb = accB[n * 64 + lane] * invb;
            if (cb > 0) s += bsB[lane];
        }
#pragma unroll
        for (int k = 0; k < 64; ++k) {
            s = fmaf(__shfl(xa, k), WTa[k][lane], s);
            if (TWO) s = fmaf(__shfl(xb, k), WTb[k][lane], s);
        }
        out[n * 64 + lane] = s;
    }
}

extern "C" void kernel_launch(void* const* d_in, const int* in_sizes, int n_in,
                              void* d_out, int out_size, void* d_ws, size_t ws_size,
                              hipStream_t stream)
{
    const float* feat_user = (const float*)d_in[0];
    const float* feat_item = (const float*)d_in[1];
    const float* W_f  = (const float*)d_in[2];
    const float* b_f  = (const float*)d_in[3];
    const float* W_r  = (const float*)d_in[4];
    const float* b_r  = (const float*)d_in[5];
    const float* W_rb = (const float*)d_in[6];
    const float* b_rb = (const float*)d_in[7];
    const int* src_f  = (const int*)d_in[8];
    const int* dst_f  = (const int*)d_in[9];
    const int* src_r  = (const int*)d_in[10];
    const int* dst_r  = (const int*)d_in[11];
    const int* src_rb = (const int*)d_in[12];
    const int* dst_rb = (const int*)d_in[13];
    float* out = (float*)d_out;

    const int NU = in_sizes[0] / D;   // 100000 user nodes
    const int NI = in_sizes[1] / D;   // 100000 item nodes
    const int Ef  = in_sizes[8];
    const int Erb = in_sizes[12];
    const int Er  = in_sizes[10];

    // Workspace layout: 3 accumulator tables + 3 count arrays.
    float* acc_f  = (float*)d_ws;
    float* acc_rb = acc_f + (size_t)NU * D;
    float* acc_r  = acc_rb + (size_t)NU * D;
    int* cnt_f  = (int*)(acc_r + (size_t)NI * D);
    int* cnt_rb = cnt_f + NU;
    int* cnt_r  = cnt_rb + NU;
    const size_t zero_bytes = ((size_t)(2 * NU + NI) * D) * sizeof(float)
                            + ((size_t)(2 * NU + NI)) * sizeof(int);
    hipMemsetAsync(d_ws, 0, zero_bytes, stream);

    const dim3 blk(256);
    scatter_mean<<<2048, blk, 0, stream>>>(feat_user, src_f,  dst_f,  acc_f,  cnt_f,  Ef);
    scatter_mean<<<2048, blk, 0, stream>>>(feat_item, src_rb, dst_rb, acc_rb, cnt_rb, Erb);
    scatter_mean<<<2048, blk, 0, stream>>>(feat_user, src_r,  dst_r,  acc_r,  cnt_r,  Er);

    finalize_nodes<true><<<1024, blk, 0, stream>>>(
        acc_f, cnt_f, W_f, b_f, acc_rb, cnt_rb, W_rb, b_rb, out, NU);
    finalize_nodes<false><<<1024, blk, 0, stream>>>(
        acc_r, cnt_r, W_r, b_r, nullptr, nullptr, nullptr, nullptr,
        out + (size_t)NU * D, NI);
}

// Round 2
// 1402.818 us; speedup vs baseline: 1.0545x; 1.0545x over previous
//
#include <hip/hip_runtime.h>

#define D 64
#define SCAN_CHUNK 1024  // items per scan block (256 thr x 4)

// ---------------- pass 1: per-dst degree histogram, all 3 etypes ----------------
__global__ __launch_bounds__(256) void hist_all(
    const int* __restrict__ d0, const int* __restrict__ d1, const int* __restrict__ d2,
    int* __restrict__ c0, int* __restrict__ c1, int* __restrict__ c2, int nE)
{
    const int et = blockIdx.y;
    const int* dst = et == 0 ? d0 : (et == 1 ? d1 : d2);
    int* cnt = et == 0 ? c0 : (et == 1 ? c1 : c2);
    for (int e = blockIdx.x * blockDim.x + threadIdx.x; e < nE; e += gridDim.x * blockDim.x)
        atomicAdd(&cnt[dst[e]], 1);
}

// ---------------- pass 2a: per-block exclusive scan of degrees ----------------
__global__ __launch_bounds__(256) void scan_blocks(
    const int* __restrict__ c0, const int* __restrict__ c1, const int* __restrict__ c2,
    int* __restrict__ r0, int* __restrict__ r1, int* __restrict__ r2,
    int* __restrict__ bsum, int N)
{
    const int et = blockIdx.y;
    const int* cnt = et == 0 ? c0 : (et == 1 ? c1 : c2);
    int* rp = et == 0 ? r0 : (et == 1 ? r1 : r2);
    const int tid = threadIdx.x;
    const int base = blockIdx.x * SCAN_CHUNK + tid * 4;

    int4 v = make_int4(0, 0, 0, 0);
    if (base + 3 < N) v = *reinterpret_cast<const int4*>(cnt + base);
    else if (base < N) {
        v.x = cnt[base];
        if (base + 1 < N) v.y = cnt[base + 1];
        if (base + 2 < N) v.z = cnt[base + 2];
    }
    const int tsum = v.x + v.y + v.z + v.w;

    int inc = tsum;  // wave-inclusive scan of per-thread sums
#pragma unroll
    for (int off = 1; off < 64; off <<= 1) {
        int t = __shfl_up(inc, off);
        if ((tid & 63) >= off) inc += t;
    }
    __shared__ int wsum[4];
    if ((tid & 63) == 63) wsum[tid >> 6] = inc;
    __syncthreads();
    int woff = 0;
    for (int i = 0; i < (tid >> 6); ++i) woff += wsum[i];
    const int excl = woff + inc - tsum;

    if (base < N) {
        int run = excl;
        rp[base] = run; run += v.x;
        if (base + 1 < N) { rp[base + 1] = run; run += v.y; }
        if (base + 2 < N) { rp[base + 2] = run; run += v.z; }
        if (base + 3 < N) { rp[base + 3] = run; }
    }
    if (tid == 255) bsum[et * 256 + blockIdx.x] = excl + tsum;
}

// ---------------- pass 2b: exclusive scan of the block totals (1 block/etype) ----------------
__global__ __launch_bounds__(128) void scan_totals(int* __restrict__ bsum, int nblk)
{
    int* bs = bsum + blockIdx.x * 256;
    const int tid = threadIdx.x;
    const int v = tid < nblk ? bs[tid] : 0;
    int inc = v;
#pragma unroll
    for (int off = 1; off < 64; off <<= 1) {
        int t = __shfl_up(inc, off);
        if ((tid & 63) >= off) inc += t;
    }
    __shared__ int ws[2];
    if ((tid & 63) == 63) ws[tid >> 6] = inc;
    __syncthreads();
    const int excl = inc - v + ((tid >> 6) ? ws[0] : 0);
    bs[tid] = excl;
}

// ---------------- pass 2c: add block offsets -> rowptr; init cursor ----------------
__global__ __launch_bounds__(256) void add_offsets(
    int* __restrict__ r0, int* __restrict__ r1, int* __restrict__ r2,
    int* __restrict__ u0, int* __restrict__ u1, int* __restrict__ u2,
    const int* __restrict__ bsum, int N)
{
    const int et = blockIdx.y;
    int* rp = et == 0 ? r0 : (et == 1 ? r1 : r2);
    int* cur = et == 0 ? u0 : (et == 1 ? u1 : u2);
    const int off = bsum[et * 256 + blockIdx.x];
    const int base = blockIdx.x * SCAN_CHUNK + threadIdx.x * 4;
    if (base + 3 < N) {
        int4 v = *reinterpret_cast<int4*>(rp + base);
        v.x += off; v.y += off; v.z += off; v.w += off;
        *reinterpret_cast<int4*>(rp + base) = v;
        *reinterpret_cast<int4*>(cur + base) = v;
    } else {
        for (int j = 0; j < 4; ++j) {
            if (base + j < N) { int t = rp[base + j] + off; rp[base + j] = t; cur[base + j] = t; }
        }
    }
}

// ---------------- pass 3: fill edge lists (src ids grouped by dst) ----------------
__global__ __launch_bounds__(256) void fill_all(
    const int* __restrict__ s0, const int* __restrict__ d0,
    const int* __restrict__ s1, const int* __restrict__ d1,
    const int* __restrict__ s2, const int* __restrict__ d2,
    int* __restrict__ u0, int* __restrict__ u1, int* __restrict__ u2,
    int* __restrict__ l0, int* __restrict__ l1, int* __restrict__ l2, int nE)
{
    const int et = blockIdx.y;
    const int* src = et == 0 ? s0 : (et == 1 ? s1 : s2);
    const int* dst = et == 0 ? d0 : (et == 1 ? d1 : d2);
    int* cur = et == 0 ? u0 : (et == 1 ? u1 : u2);
    int* lst = et == 0 ? l0 : (et == 1 ? l1 : l2);
    for (int e = blockIdx.x * blockDim.x + threadIdx.x; e < nE; e += gridDim.x * blockDim.x) {
        const int d = dst[e];
        const int pos = atomicAdd(&cur[d], 1);
        lst[pos] = src[e];
    }
}

// ---------------- pass 4: per-dst gather + mean + fused projection ----------------
// One wave per node, lane = feature dim. TWO: user nodes (follows + ratedby).
template <bool TWO>
__global__ __launch_bounds__(256) void gather_project(
    const float* __restrict__ featA, const int* __restrict__ rpA,
    const int* __restrict__ cntA, const int* __restrict__ lstA,
    const float* __restrict__ WA, const float* __restrict__ bA,
    const float* __restrict__ featB, const int* __restrict__ rpB,
    const int* __restrict__ cntB, const int* __restrict__ lstB,
    const float* __restrict__ WB, const float* __restrict__ bB,
    float* __restrict__ out, int N)
{
    __shared__ float WTa[64][64];
    __shared__ float WTb[TWO ? 64 : 1][64];
    __shared__ float bsA[64];
    __shared__ float bsB[64];
    for (int i = threadIdx.x; i < 4096; i += 256) {
        const int dd = i >> 6, k = i & 63;
        WTa[k][dd] = WA[i];
        if (TWO) WTb[k][dd] = WB[i];
    }
    if (threadIdx.x < 64) {
        bsA[threadIdx.x] = bA[threadIdx.x];
        bsB[threadIdx.x] = TWO ? bB[threadIdx.x] : 0.0f;
    }
    __syncthreads();

    const int lane = threadIdx.x & 63;
    const int w = threadIdx.x >> 6;
    for (int n = blockIdx.x * 4 + w; n < N; n += gridDim.x * 4) {
        const int da = cntA[n], sa = rpA[n];
        float sumA = 0.0f;
        int i = 0;
        for (; i + 1 < da; i += 2) {
            const int a = lstA[sa + i], b = lstA[sa + i + 1];
            sumA += featA[a * D + lane] + featA[b * D + lane];
        }
        if (i < da) sumA += featA[lstA[sa + i] * D + lane];
        const float ma = da > 0 ? sumA / (float)da : 0.0f;

        float mb = 0.0f;
        int db = 0;
        if (TWO) {
            db = cntB[n];
            const int sb = rpB[n];
            float sumB = 0.0f;
            i = 0;
            for (; i + 1 < db; i += 2) {
                const int a = lstB[sb + i], b = lstB[sb + i + 1];
                sumB += featB[a * D + lane] + featB[b * D + lane];
            }
            if (i < db) sumB += featB[lstB[sb + i] * D + lane];
            mb = db > 0 ? sumB / (float)db : 0.0f;
        }

        float s = (da > 0 ? bsA[lane] : 0.0f);
        if (TWO && db > 0) s += bsB[lane];
#pragma unroll
        for (int k = 0; k < 64; ++k) {
            s = fmaf(__shfl(ma, k), WTa[k][lane], s);
            if (TWO) s = fmaf(__shfl(mb, k), WTb[k][lane], s);
        }
        out[n * D + lane] = s;
    }
}

extern "C" void kernel_launch(void* const* d_in, const int* in_sizes, int n_in,
                              void* d_out, int out_size, void* d_ws, size_t ws_size,
                              hipStream_t stream)
{
    const float* feat_user = (const float*)d_in[0];
    const float* feat_item = (const float*)d_in[1];
    const float* W_f  = (const float*)d_in[2];
    const float* b_f  = (const float*)d_in[3];
    const float* W_r  = (const float*)d_in[4];
    const float* b_r  = (const float*)d_in[5];
    const float* W_rb = (const float*)d_in[6];
    const float* b_rb = (const float*)d_in[7];
    const int* src_f  = (const int*)d_in[8];
    const int* dst_f  = (const int*)d_in[9];
    const int* src_r  = (const int*)d_in[10];
    const int* dst_r  = (const int*)d_in[11];
    const int* src_rb = (const int*)d_in[12];
    const int* dst_rb = (const int*)d_in[13];
    float* out = (float*)d_out;

    const int NU = in_sizes[0] / D;   // 100000
    const int NI = in_sizes[1] / D;   // 100000 (== NU)
    const int E  = in_sizes[8];       // 1.6M per etype
    const int N  = NU;                // NU == NI
    const int nblk = (N + SCAN_CHUNK - 1) / SCAN_CHUNK;  // 98

    // Workspace layout (all int):
    int* cnt_f  = (int*)d_ws;             // [N] degrees
    int* cnt_rb = cnt_f  + N;
    int* cnt_r  = cnt_rb + N;
    int* rp_f   = cnt_r  + N;             // [N] rowptr (exclusive scan)
    int* rp_rb  = rp_f   + N;
    int* rp_r   = rp_rb  + N;
    int* cur_f  = rp_r   + N;             // [N] fill cursors
    int* cur_rb = cur_f  + N;
    int* cur_r  = cur_rb + N;
    int* bsum   = cur_r  + N;             // [3*256] block sums
    int* lst_f  = bsum   + 3 * 256;       // [E] src ids grouped by dst
    int* lst_rb = lst_f  + E;
    int* lst_r  = lst_rb + E;

    hipMemsetAsync(d_ws, 0, (size_t)3 * N * sizeof(int), stream);

    const dim3 blk(256);
    hist_all<<<dim3(1024, 3), blk, 0, stream>>>(dst_f, dst_rb, dst_r,
                                                cnt_f, cnt_rb, cnt_r, E);
    scan_blocks<<<dim3(nblk, 3), blk, 0, stream>>>(cnt_f, cnt_rb, cnt_r,
                                                   rp_f, rp_rb, rp_r, bsum, N);
    scan_totals<<<3, 128, 0, stream>>>(bsum, nblk);
    add_offsets<<<dim3(nblk, 3), blk, 0, stream>>>(rp_f, rp_rb, rp_r,
                                                   cur_f, cur_rb, cur_r, bsum, N);
    fill_all<<<dim3(1024, 3), blk, 0, stream>>>(src_f, dst_f, src_rb, dst_rb, src_r, dst_r,
                                                cur_f, cur_rb, cur_r,
                                                lst_f, lst_rb, lst_r, E);
    // Users: follows (src=user) + ratedby (src=item), cross-reducer 'sum'.
    gather_project<true><<<2048, blk, 0, stream>>>(
        feat_user, rp_f, cnt_f, lst_f, W_f, b_f,
        feat_item, rp_rb, cnt_rb, lst_rb, W_rb, b_rb,
        out, NU);
    // Items: rates (src=user).
    gather_project<false><<<2048, blk, 0, stream>>>(
        feat_user, rp_r, cnt_r, lst_r, W_r, b_r,
        nullptr, nullptr, nullptr, nullptr, nullptr, nullptr,
        out + (size_t)NU * D, NI);
}

// Round 3
// 1052.546 us; speedup vs baseline: 1.4055x; 1.3328x over previous
//
#include <hip/hip_runtime.h>

#define D 64
#define SCAN_CHUNK 1024  // items per scan block (256 thr x 4)

// ---------------- pass 1: per-dst degree histogram, all 3 etypes ----------------
__global__ __launch_bounds__(256) void hist_all(
    const int* __restrict__ d0, const int* __restrict__ d1, const int* __restrict__ d2,
    int* __restrict__ c0, int* __restrict__ c1, int* __restrict__ c2, int nE)
{
    const int et = blockIdx.y;
    const int* dst = et == 0 ? d0 : (et == 1 ? d1 : d2);
    int* cnt = et == 0 ? c0 : (et == 1 ? c1 : c2);
    for (int e = blockIdx.x * blockDim.x + threadIdx.x; e < nE; e += gridDim.x * blockDim.x)
        atomicAdd(&cnt[dst[e]], 1);
}

// ---------------- pass 2a: per-block exclusive scan of degrees ----------------
__global__ __launch_bounds__(256) void scan_blocks(
    const int* __restrict__ c0, const int* __restrict__ c1, const int* __restrict__ c2,
    int* __restrict__ r0, int* __restrict__ r1, int* __restrict__ r2,
    int* __restrict__ bsum, int N)
{
    const int et = blockIdx.y;
    const int* cnt = et == 0 ? c0 : (et == 1 ? c1 : c2);
    int* rp = et == 0 ? r0 : (et == 1 ? r1 : r2);
    const int tid = threadIdx.x;
    const int base = blockIdx.x * SCAN_CHUNK + tid * 4;

    int4 v = make_int4(0, 0, 0, 0);
    if (base + 3 < N) v = *reinterpret_cast<const int4*>(cnt + base);
    else if (base < N) {
        v.x = cnt[base];
        if (base + 1 < N) v.y = cnt[base + 1];
        if (base + 2 < N) v.z = cnt[base + 2];
    }
    const int tsum = v.x + v.y + v.z + v.w;

    int inc = tsum;  // wave-inclusive scan of per-thread sums
#pragma unroll
    for (int off = 1; off < 64; off <<= 1) {
        int t = __shfl_up(inc, off);
        if ((tid & 63) >= off) inc += t;
    }
    __shared__ int wsum[4];
    if ((tid & 63) == 63) wsum[tid >> 6] = inc;
    __syncthreads();
    int woff = 0;
    for (int i = 0; i < (tid >> 6); ++i) woff += wsum[i];
    const int excl = woff + inc - tsum;

    if (base < N) {
        int run = excl;
        rp[base] = run; run += v.x;
        if (base + 1 < N) { rp[base + 1] = run; run += v.y; }
        if (base + 2 < N) { rp[base + 2] = run; run += v.z; }
        if (base + 3 < N) { rp[base + 3] = run; }
    }
    if (tid == 255) bsum[et * 256 + blockIdx.x] = excl + tsum;
}

// ---------------- pass 2b: exclusive scan of the block totals (1 block/etype) ----------------
__global__ __launch_bounds__(128) void scan_totals(int* __restrict__ bsum, int nblk)
{
    int* bs = bsum + blockIdx.x * 256;
    const int tid = threadIdx.x;
    const int v = tid < nblk ? bs[tid] : 0;
    int inc = v;
#pragma unroll
    for (int off = 1; off < 64; off <<= 1) {
        int t = __shfl_up(inc, off);
        if ((tid & 63) >= off) inc += t;
    }
    __shared__ int ws[2];
    if ((tid & 63) == 63) ws[tid >> 6] = inc;
    __syncthreads();
    const int excl = inc - v + ((tid >> 6) ? ws[0] : 0);
    bs[tid] = excl;
}

// ---------------- pass 2c: add block offsets -> rowptr; init cursor ----------------
__global__ __launch_bounds__(256) void add_offsets(
    int* __restrict__ r0, int* __restrict__ r1, int* __restrict__ r2,
    int* __restrict__ u0, int* __restrict__ u1, int* __restrict__ u2,
    const int* __restrict__ bsum, int N)
{
    const int et = blockIdx.y;
    int* rp = et == 0 ? r0 : (et == 1 ? r1 : r2);
    int* cur = et == 0 ? u0 : (et == 1 ? u1 : u2);
    const int off = bsum[et * 256 + blockIdx.x];
    const int base = blockIdx.x * SCAN_CHUNK + threadIdx.x * 4;
    if (base + 3 < N) {
        int4 v = *reinterpret_cast<int4*>(rp + base);
        v.x += off; v.y += off; v.z += off; v.w += off;
        *reinterpret_cast<int4*>(rp + base) = v;
        *reinterpret_cast<int4*>(cur + base) = v;
    } else {
        for (int j = 0; j < 4; ++j) {
            if (base + j < N) { int t = rp[base + j] + off; rp[base + j] = t; cur[base + j] = t; }
        }
    }
}

// ---------------- pass 3: fill edge lists (src ids grouped by dst) ----------------
__global__ __launch_bounds__(256) void fill_all(
    const int* __restrict__ s0, const int* __restrict__ d0,
    const int* __restrict__ s1, const int* __restrict__ d1,
    const int* __restrict__ s2, const int* __restrict__ d2,
    int* __restrict__ u0, int* __restrict__ u1, int* __restrict__ u2,
    int* __restrict__ l0, int* __restrict__ l1, int* __restrict__ l2, int nE)
{
    const int et = blockIdx.y;
    const int* src = et == 0 ? s0 : (et == 1 ? s1 : s2);
    const int* dst = et == 0 ? d0 : (et == 1 ? d1 : d2);
    int* cur = et == 0 ? u0 : (et == 1 ? u1 : u2);
    int* lst = et == 0 ? l0 : (et == 1 ? l1 : l2);
    for (int e = blockIdx.x * blockDim.x + threadIdx.x; e < nE; e += gridDim.x * blockDim.x) {
        const int d = dst[e];
        const int pos = atomicAdd(&cur[d], 1);
        lst[pos] = src[e];
    }
}

// ---------------- pass 4: per-dst gather + mean + fused projection, 1 etype ----------------
// One wave per node, lane = output dim. 8-deep load pipeline for MLP.
// RMW: add to existing out (cross-etype 'sum' reducer; stream-serialized, race-free).
template <bool RMW>
__global__ __launch_bounds__(256) void gather_proj(
    const float* __restrict__ feat, const int* __restrict__ rp,
    const int* __restrict__ cnt, const int* __restrict__ lst,
    const float* __restrict__ W, const float* __restrict__ bias,
    float* __restrict__ out, int N)
{
    __shared__ float WT[64][65];  // [k][o], pad -> conflict-free staging AND reads
    __shared__ float bs[64];
    for (int i = threadIdx.x; i < 4096; i += 256)
        WT[i & 63][i >> 6] = W[i];  // W[o*64+k] -> WT[k][o]
    if (threadIdx.x < 64) bs[threadIdx.x] = bias[threadIdx.x];
    __syncthreads();

    const int lane = threadIdx.x & 63;
    const int n = blockIdx.x * 4 + (threadIdx.x >> 6);
    if (n >= N) return;

    const int deg = cnt[n];
    const int start = rp[n];
    float s0 = 0.0f, s1 = 0.0f;
    for (int base = 0; base < deg; base += 8) {
        int idx[8];
        float f[8];
#pragma unroll
        for (int j = 0; j < 8; ++j)
            idx[j] = (base + j < deg) ? lst[start + base + j] : -1;
#pragma unroll
        for (int j = 0; j < 8; ++j)
            f[j] = feat[(idx[j] < 0 ? 0 : idx[j]) * D + lane];  // always issue the load
#pragma unroll
        for (int j = 0; j < 8; ++j) {
            const float v = idx[j] < 0 ? 0.0f : f[j];
            if (j & 1) s1 += v; else s0 += v;
        }
    }
    const float m = deg > 0 ? (s0 + s1) / (float)deg : 0.0f;

    float a0 = deg > 0 ? bs[lane] : 0.0f;
    float a1 = 0.0f, a2 = 0.0f, a3 = 0.0f;
#pragma unroll
    for (int k = 0; k < 64; k += 4) {
        a0 = fmaf(__shfl(m, k + 0), WT[k + 0][lane], a0);
        a1 = fmaf(__shfl(m, k + 1), WT[k + 1][lane], a1);
        a2 = fmaf(__shfl(m, k + 2), WT[k + 2][lane], a2);
        a3 = fmaf(__shfl(m, k + 3), WT[k + 3][lane], a3);
    }
    float r = (a0 + a1) + (a2 + a3);
    if (RMW) r += out[n * D + lane];
    out[n * D + lane] = r;
}

extern "C" void kernel_launch(void* const* d_in, const int* in_sizes, int n_in,
                              void* d_out, int out_size, void* d_ws, size_t ws_size,
                              hipStream_t stream)
{
    const float* feat_user = (const float*)d_in[0];
    const float* feat_item = (const float*)d_in[1];
    const float* W_f  = (const float*)d_in[2];
    const float* b_f  = (const float*)d_in[3];
    const float* W_r  = (const float*)d_in[4];
    const float* b_r  = (const float*)d_in[5];
    const float* W_rb = (const float*)d_in[6];
    const float* b_rb = (const float*)d_in[7];
    const int* src_f  = (const int*)d_in[8];
    const int* dst_f  = (const int*)d_in[9];
    const int* src_r  = (const int*)d_in[10];
    const int* dst_r  = (const int*)d_in[11];
    const int* src_rb = (const int*)d_in[12];
    const int* dst_rb = (const int*)d_in[13];
    float* out = (float*)d_out;

    const int NU = in_sizes[0] / D;   // 100000
    const int NI = in_sizes[1] / D;   // 100000 (== NU)
    const int E  = in_sizes[8];       // 1.6M per etype
    const int N  = NU;                // NU == NI
    const int nblk = (N + SCAN_CHUNK - 1) / SCAN_CHUNK;  // 98

    // Workspace layout (all int): ~22 MB
    int* cnt_f  = (int*)d_ws;             // [N] degrees
    int* cnt_rb = cnt_f  + N;
    int* cnt_r  = cnt_rb + N;
    int* rp_f   = cnt_r  + N;             // [N] rowptr (exclusive scan)
    int* rp_rb  = rp_f   + N;
    int* rp_r   = rp_rb  + N;
    int* cur_f  = rp_r   + N;             // [N] fill cursors
    int* cur_rb = cur_f  + N;
    int* cur_r  = cur_rb + N;
    int* bsum   = cur_r  + N;             // [3*256] block sums
    int* lst_f  = bsum   + 3 * 256;       // [E] src ids grouped by dst
    int* lst_rb = lst_f  + E;
    int* lst_r  = lst_rb + E;

    hipMemsetAsync(d_ws, 0, (size_t)3 * N * sizeof(int), stream);

    const dim3 blk(256);
    hist_all<<<dim3(1024, 3), blk, 0, stream>>>(dst_f, dst_rb, dst_r,
                                                cnt_f, cnt_rb, cnt_r, E);
    scan_blocks<<<dim3(nblk, 3), blk, 0, stream>>>(cnt_f, cnt_rb, cnt_r,
                                                   rp_f, rp_rb, rp_r, bsum, N);
    scan_totals<<<3, 128, 0, stream>>>(bsum, nblk);
    add_offsets<<<dim3(nblk, 3), blk, 0, stream>>>(rp_f, rp_rb, rp_r,
                                                   cur_f, cur_rb, cur_r, bsum, N);
    fill_all<<<dim3(1024, 3), blk, 0, stream>>>(src_f, dst_f, src_rb, dst_rb, src_r, dst_r,
                                                cur_f, cur_rb, cur_r,
                                                lst_f, lst_rb, lst_r, E);

    const int gblk = (N + 3) / 4;  // one wave per node
    // users: follows (store), then ratedby (read-modify-write) -> cross-type sum
    gather_proj<false><<<gblk, blk, 0, stream>>>(
        feat_user, rp_f, cnt_f, lst_f, W_f, b_f, out, NU);
    gather_proj<true><<<gblk, blk, 0, stream>>>(
        feat_item, rp_rb, cnt_rb, lst_rb, W_rb, b_rb, out, NU);
    // items: rates (store)
    gather_proj<false><<<gblk, blk, 0, stream>>>(
        feat_user, rp_r, cnt_r, lst_r, W_r, b_r, out + (size_t)NU * D, NI);
}